// Round 13
// baseline (144.727 us; speedup 1.0000x reference)
//
#include <hip/hip_runtime.h>
#include <hip/hip_bf16.h>
#include <hip/hip_fp16.h>

#define N_NODES 100000
#define N_EDGES 1600000
#define NBUCK ((N_NODES + 255) >> 8)   // 391 buckets of 256 nodes
#define CAP 8192                        // fixed region capacity per bucket (mean ~4096)
#define NQ (N_NODES / 4)                // 25000 quartets

typedef _Float16 f16x2 __attribute__((ext_vector_type(2)));
typedef float f32x2 __attribute__((ext_vector_type(2)));

__device__ inline float2 h2_to_f2(unsigned int u) {
    __half2 h = *reinterpret_cast<__half2*>(&u);
    return __half22float2(h);
}
__device__ inline f16x2 uf2(unsigned int u) {
    union { unsigned int u; f16x2 h; } v;
    v.u = u;
    return v.h;
}
#if __has_builtin(__builtin_amdgcn_fdot2)
#define DOT2(a, b, c) __builtin_amdgcn_fdot2((a), (b), (c), false)
#else
__device__ inline float DOT2(f16x2 a, f16x2 b, float c) {
    return c + (float)a.x * (float)b.x + (float)a.y * (float)b.y;
}
#endif

// ---------------- fp8 e4m3 (OCP) helpers ----------------
// encode: manual (half-up rounding; only 6.4M calls in layer1)
__device__ inline unsigned int f32_to_fp8(float v) {
    unsigned int s = (__float_as_uint(v) >> 24) & 0x80u;
    float a = fminf(fabsf(v), 448.0f);
    unsigned int au = __float_as_uint(a);
    int e = (int)(au >> 23) - 127;
    if (e < -9) return s;                       // -> 0
    if (e < -6) {                               // subnormal: round(a * 2^9)
        int q = (int)(a * 512.0f + 0.5f);
        if (q >= 8) return s | 0x08u;           // min normal
        return s | (unsigned int)q;
    }
    float scale = __uint_as_float((unsigned int)(127 - e) << 23);  // 2^-e
    int q = (int)(a * scale * 8.0f + 0.5f);     // [8..16]
    if (q >= 16) { e += 1; q = 8; }
    if (e > 8) return s | 0x7Eu;                // clamp to 448
    return s | ((unsigned int)(e + 7) << 3) | (unsigned int)(q - 8);
}

// decode: HW packed conversion when available (gfx950 = OCP), else bit math
#if __has_builtin(__builtin_amdgcn_cvt_pk_f32_fp8)
#define HAVE_CVT_FP8 1
#else
__device__ inline float fp8_to_f32(unsigned int b) {
    unsigned int s = b & 0x80u;
    unsigned int e = (b >> 3) & 15u;
    unsigned int m = b & 7u;
    float norm = __uint_as_float(((e + 120u) << 23) | (m << 20));
    float sub = (float)m * 0.001953125f;        // m * 2^-9
    float v = e ? norm : sub;
    return s ? -v : v;
}
#endif

__device__ inline void dec8_add(uint2 a, float* acc) {
#ifdef HAVE_CVT_FP8
    f32x2 p0 = __builtin_amdgcn_cvt_pk_f32_fp8(a.x, false);
    f32x2 p1 = __builtin_amdgcn_cvt_pk_f32_fp8(a.x, true);
    f32x2 p2 = __builtin_amdgcn_cvt_pk_f32_fp8(a.y, false);
    f32x2 p3 = __builtin_amdgcn_cvt_pk_f32_fp8(a.y, true);
    acc[0] += p0.x; acc[1] += p0.y; acc[2] += p1.x; acc[3] += p1.y;
    acc[4] += p2.x; acc[5] += p2.y; acc[6] += p3.x; acc[7] += p3.y;
#else
    acc[0] += fp8_to_f32(a.x & 255); acc[1] += fp8_to_f32((a.x >> 8) & 255);
    acc[2] += fp8_to_f32((a.x >> 16) & 255); acc[3] += fp8_to_f32(a.x >> 24);
    acc[4] += fp8_to_f32(a.y & 255); acc[5] += fp8_to_f32((a.y >> 8) & 255);
    acc[6] += fp8_to_f32((a.y >> 16) & 255); acc[7] += fp8_to_f32(a.y >> 24);
#endif
}

// ---------------------------------------------------------------------------
// Zero bcursor + gsum (tiny; NOT hipMemsetAsync — rocclr blit node overhead)
// ---------------------------------------------------------------------------
__global__ void k_zero(int* __restrict__ p, int n) {
    for (int i = threadIdx.x; i < n; i += 256) p[i] = 0;
}

// ---------------------------------------------------------------------------
// CSR build pass 1: stage edges into fixed-capacity bucket regions.
// ---------------------------------------------------------------------------
__global__ __launch_bounds__(256) void k_stage(const int* __restrict__ src,
                                               const int* __restrict__ dst,
                                               int* __restrict__ bcursor,
                                               unsigned int* __restrict__ stage) {
    __shared__ int h[NBUCK];
    __shared__ int base[NBUCK];
    __shared__ int cur[NBUCK];
    const int epb = (N_EDGES + gridDim.x - 1) / gridDim.x;
    const int c0 = blockIdx.x * epb;
    const int c1 = (c0 + epb < N_EDGES) ? (c0 + epb) : N_EDGES;

    for (int i = threadIdx.x; i < NBUCK; i += 256) { h[i] = 0; cur[i] = 0; }
    __syncthreads();
    for (int e = c0 + threadIdx.x; e < c1; e += 256)
        atomicAdd(&h[dst[e] >> 8], 1);
    __syncthreads();
    for (int i = threadIdx.x; i < NBUCK; i += 256)
        base[i] = h[i] ? atomicAdd(&bcursor[i], h[i]) : 0;
    __syncthreads();
    for (int e = c0 + threadIdx.x; e < c1; e += 256) {
        int d = dst[e];
        int b = d >> 8;
        int pos = base[b] + atomicAdd(&cur[b], 1);
        if (pos < CAP)  // overflow guard (P ~ 0 for this graph)
            stage[b * CAP + pos] = ((unsigned int)(d & 255) << 17) | (unsigned int)src[e];
    }
}

// ---------------------------------------------------------------------------
// CSR build pass 2: one block (512 thr) per bucket; LDS counting-sort IN
// PLACE. Emits row_start[node] = b*CAP + local_excl_offset and deg[node].
// ---------------------------------------------------------------------------
__global__ __launch_bounds__(512) void k_bsort(unsigned int* __restrict__ stage,
                                               const int* __restrict__ bcursor,
                                               int* __restrict__ row_start,
                                               int* __restrict__ deg) {
    __shared__ int off[256];
    __shared__ int cur[256];
    __shared__ unsigned int out[CAP];
    const int b = blockIdx.x;
    int cnt = bcursor[b];
    if (cnt > CAP) cnt = CAP;
    const int s = b * CAP;
    const int tid = threadIdx.x;

    if (tid < 256) cur[tid] = 0;
    __syncthreads();
    for (int i = tid; i < cnt; i += 512)
        atomicAdd(&cur[stage[s + i] >> 17], 1);
    __syncthreads();
    int v = 0;
    if (tid < 256) {
        v = cur[tid];
        off[tid] = v;
    }
    __syncthreads();
    for (int d = 1; d < 256; d <<= 1) {
        int t = 0;
        if (tid < 256 && tid >= d) t = off[tid - d];
        __syncthreads();
        if (tid < 256) off[tid] += t;
        __syncthreads();
    }
    if (tid < 256) {
        int ex = off[tid] - v;
        off[tid] = ex;
        cur[tid] = 0;
        int node = b * 256 + tid;
        if (node < N_NODES) {
            row_start[node] = s + ex;
            deg[node] = v;
        }
    }
    __syncthreads();

    for (int i = tid; i < cnt; i += 512) {
        unsigned int p = stage[s + i];
        int l = p >> 17;
        int pos = off[l] + atomicAdd(&cur[l], 1);
        out[pos] = p & 0x1FFFFu;
    }
    __syncthreads();
    for (int i = tid; i < cnt; i += 512)
        stage[s + i] = out[i];
}

// ---------------------------------------------------------------------------
// Layer 1 fused: one wave per node, 8 neighbors per load, shfl-reduce,
// 8->64 MLP with weights in regs; writes h1 as BOTH fp16 (for mlp2 stream)
// and fp8 (for agg2's random gather — 64B row = one cache line).
// ---------------------------------------------------------------------------
__global__ __launch_bounds__(256) void layer1(
    const float* __restrict__ x, const int* __restrict__ row_start,
    const int* __restrict__ deg, const int* __restrict__ csr,
    const float* __restrict__ W1l, const float* __restrict__ b1,
    const float* __restrict__ W1r, __half* __restrict__ h1h,
    unsigned char* __restrict__ h1q) {
    const int lane = threadIdx.x & 63;
    const int g = lane >> 3;
    const int sub = lane & 7;

    float wl1[8], wr1[8];
#pragma unroll
    for (int k = 0; k < 8; k++) {
        wl1[k] = W1l[k * 64 + lane];
        wr1[k] = W1r[k * 64 + lane];
    }
    float bv = b1[lane];
    asm volatile("" ::: "memory");

    const int gwid = (blockIdx.x * blockDim.x + threadIdx.x) >> 6;
    const int nwaves = (gridDim.x * blockDim.x) >> 6;

    for (int node = gwid; node < N_NODES; node += nwaves) {
        int rs = row_start[node];
        int dg = deg[node];
        int re = rs + dg;
        float acc = 0.0f;
        int t = rs;
        for (; t + 16 <= re; t += 16) {
            int i0 = csr[t + g];
            int i1 = csr[t + 8 + g];
            acc += x[i0 * 8 + sub] + x[i1 * 8 + sub];
        }
        for (; t + 8 <= re; t += 8) {
            int i0 = csr[t + g];
            acc += x[i0 * 8 + sub];
        }
        int r = re - t;
        if (r > 0) {
            int ii = csr[(t + g < re) ? (t + g) : (re - 1)];
            float v = x[ii * 8 + sub];
            if (g < r) acc += v;
        }
        acc += __shfl_xor(acc, 8);
        acc += __shfl_xor(acc, 16);
        acc += __shfl_xor(acc, 32);
        float inv = 1.0f / fmaxf((float)dg, 1.0f);
        float mean = acc * inv;
        float xself = x[node * 8 + sub];
        float m[8], xk[8];
#pragma unroll
        for (int k = 0; k < 8; k++) {
            m[k]  = __shfl(mean, k);
            xk[k] = __shfl(xself, k);
        }
        float a = bv;
#pragma unroll
        for (int k = 0; k < 8; k++)
            a += m[k] * wl1[k] + xk[k] * wr1[k];
        float rl = fmaxf(a, 0.0f);
        h1h[(size_t)node * 64 + lane] = __float2half(rl);
        h1q[(size_t)node * 64 + lane] = (unsigned char)f32_to_fp8(rl);
    }
}

// ---------------------------------------------------------------------------
// Layer 2 aggregation: one wave per node, fp8 rows (64B = 1 line), 8 lanes
// per row x uint2 -> 8 neighbors per load instruction. fp32 accumulate,
// 3-level shfl reduce, lanes 0..7 write the fp16 mean row (uint4 each).
// ---------------------------------------------------------------------------
__global__ __launch_bounds__(256) void agg2(
    const unsigned char* __restrict__ h1q, const int* __restrict__ row_start,
    const int* __restrict__ deg, const int* __restrict__ csr,
    __half* __restrict__ mean2h) {
    const int lane = threadIdx.x & 63;
    const int g = lane >> 3;      // neighbor slot 0..7
    const int sub = lane & 7;     // byte chunk: feats 8*sub..8*sub+7

    const int gwid = (blockIdx.x * blockDim.x + threadIdx.x) >> 6;
    const int nwaves = (gridDim.x * blockDim.x) >> 6;

    for (int node = gwid; node < N_NODES; node += nwaves) {
        int rs = row_start[node];
        int dg = deg[node];
        int re = rs + dg;
        float acc[8];
#pragma unroll
        for (int j = 0; j < 8; j++) acc[j] = 0.0f;
        int t = rs;
        for (; t + 8 <= re; t += 8) {
            int i0 = csr[t + g];
            uint2 a = *(const uint2*)(h1q + (size_t)i0 * 64 + sub * 8);
            dec8_add(a, acc);
        }
        int r = re - t;  // 0..7
        if (r > 0) {
            int ii = csr[(t + g < re) ? (t + g) : (re - 1)];
            uint2 a = *(const uint2*)(h1q + (size_t)ii * 64 + sub * 8);
            if (g < r) dec8_add(a, acc);
        }
        // reduce across the 8 neighbor slots (xor 8,16,32)
#pragma unroll
        for (int mm = 8; mm <= 32; mm <<= 1) {
#pragma unroll
            for (int j = 0; j < 8; j++)
                acc[j] += __shfl_xor(acc[j], mm);
        }
        float inv = 1.0f / fmaxf((float)dg, 1.0f);
        if (g == 0) {  // lanes 0..7: features sub*8 .. sub*8+7
            __half2 o0 = __floats2half2_rn(acc[0] * inv, acc[1] * inv);
            __half2 o1 = __floats2half2_rn(acc[2] * inv, acc[3] * inv);
            __half2 o2 = __floats2half2_rn(acc[4] * inv, acc[5] * inv);
            __half2 o3 = __floats2half2_rn(acc[6] * inv, acc[7] * inv);
            uint4 pk;
            pk.x = *(unsigned int*)&o0;
            pk.y = *(unsigned int*)&o1;
            pk.z = *(unsigned int*)&o2;
            pk.w = *(unsigned int*)&o3;
            *(uint4*)(mean2h + (size_t)node * 64 + sub * 8) = pk;
        }
    }
}

// ---------------------------------------------------------------------------
// Layer 2 MLP + global mean pool. Quartet-per-wave, double-buffered private
// LDS staging, packed half2 weights via v_dot2_f32_f16. (Kept SEPARATE from
// agg2: fusing demotes the 64 weight VGPRs to scratch — round-8 lesson.)
// ---------------------------------------------------------------------------
__global__ __launch_bounds__(256) void mlp2(
    const __half* __restrict__ mean2h, const __half* __restrict__ h1h,
    const float* __restrict__ W2l, const float* __restrict__ b2,
    const float* __restrict__ W2r, float* __restrict__ gsum) {
    __shared__ __align__(16) unsigned short sh[4][2][512];
    __shared__ float part[4][64];
    const int tid = threadIdx.x;
    const int lane = tid & 63;
    const int w = tid >> 6;

    f16x2 w2[64];
#pragma unroll
    for (int k2 = 0; k2 < 32; k2++) {
        f16x2 t;
        t.x = (_Float16)W2l[(2 * k2) * 64 + lane];
        t.y = (_Float16)W2l[(2 * k2 + 1) * 64 + lane];
        w2[k2] = t;
        f16x2 u;
        u.x = (_Float16)W2r[(2 * k2) * 64 + lane];
        u.y = (_Float16)W2r[(2 * k2 + 1) * 64 + lane];
        w2[32 + k2] = u;
    }
    float bv = b2[lane];
    asm volatile("" ::: "memory");

    const int n = lane >> 4;
    const int r = (lane >> 3) & 1;
    const int c = lane & 7;
    const __half* sbase = r ? h1h : mean2h;

    const int gwid = (blockIdx.x * blockDim.x + tid) >> 6;
    const int nwaves = (gridDim.x * blockDim.x) >> 6;
    float pool = 0.0f;

    int q = gwid;
    uint4 cur = {0, 0, 0, 0};
    if (q < NQ)
        cur = *(const uint4*)(sbase + (size_t)(q * 4 + n) * 64 + c * 8);
    int p = 0;
    while (q < NQ) {
        *(uint4*)&sh[w][p][lane * 8] = cur;
        int qn = q + nwaves;
        uint4 nxt = {0, 0, 0, 0};
        if (qn < NQ)
            nxt = *(const uint4*)(sbase + (size_t)(qn * 4 + n) * 64 + c * 8);
        const uint4* rows = (const uint4*)&sh[w][p][0];
        float a0 = bv, a1 = bv, a2 = bv, a3 = bv;
#pragma unroll
        for (int cc = 0; cc < 16; cc++) {
            uint4 r0 = rows[cc];
            uint4 r1 = rows[16 + cc];
            uint4 r2 = rows[32 + cc];
            uint4 r3 = rows[48 + cc];
            f16x2 wa = w2[cc * 4 + 0], wb = w2[cc * 4 + 1];
            f16x2 wc = w2[cc * 4 + 2], wd = w2[cc * 4 + 3];
            a0 = DOT2(uf2(r0.x), wa, a0); a0 = DOT2(uf2(r0.y), wb, a0);
            a0 = DOT2(uf2(r0.z), wc, a0); a0 = DOT2(uf2(r0.w), wd, a0);
            a1 = DOT2(uf2(r1.x), wa, a1); a1 = DOT2(uf2(r1.y), wb, a1);
            a1 = DOT2(uf2(r1.z), wc, a1); a1 = DOT2(uf2(r1.w), wd, a1);
            a2 = DOT2(uf2(r2.x), wa, a2); a2 = DOT2(uf2(r2.y), wb, a2);
            a2 = DOT2(uf2(r2.z), wc, a2); a2 = DOT2(uf2(r2.w), wd, a2);
            a3 = DOT2(uf2(r3.x), wa, a3); a3 = DOT2(uf2(r3.y), wb, a3);
            a3 = DOT2(uf2(r3.z), wc, a3); a3 = DOT2(uf2(r3.w), wd, a3);
        }
        pool += fmaxf(a0, 0.0f) + fmaxf(a1, 0.0f) +
                fmaxf(a2, 0.0f) + fmaxf(a3, 0.0f);
        cur = nxt;
        p ^= 1;
        q = qn;
    }

    part[w][lane] = pool;
    __syncthreads();
    if (tid < 64)
        atomicAdd(&gsum[tid],
                  part[0][tid] + part[1][tid] + part[2][tid] + part[3][tid]);
}

// ---------------------------------------------------------------------------
// Head
// ---------------------------------------------------------------------------
__global__ void head(const float* __restrict__ gsum,
                     const float* __restrict__ fc1W, const float* __restrict__ fc1b,
                     const float* __restrict__ fc2W, const float* __restrict__ fc2b,
                     float* __restrict__ out) {
    __shared__ float g[64];
    __shared__ float a1[64];
    __shared__ float a2[10];
    int j = threadIdx.x;
    g[j] = gsum[j] * (1.0f / (float)N_NODES);
    __syncthreads();
    float acc = fc1b[j];
    for (int k = 0; k < 64; k++) acc += g[k] * fc1W[k * 64 + j];
    a1[j] = fmaxf(acc, 0.0f);
    __syncthreads();
    if (j < 10) {
        float acc2 = fc2b[j];
        for (int k = 0; k < 64; k++) acc2 += a1[k] * fc2W[k * 10 + j];
        a2[j] = acc2;
    }
    __syncthreads();
    if (j == 0) {
        float mx = -1e30f;
        for (int i = 0; i < 10; i++) mx = fmaxf(mx, a2[i]);
        float s = 0.0f;
        float e[10];
        for (int i = 0; i < 10; i++) {
            e[i] = expf(a2[i] - mx);
            s += e[i];
        }
        float invs = 1.0f / s;
        for (int i = 0; i < 10; i++) out[i] = e[i] * invs;
    }
}

extern "C" void kernel_launch(void* const* d_in, const int* in_sizes, int n_in,
                              void* d_out, int out_size, void* d_ws, size_t ws_size,
                              hipStream_t stream) {
    const float* x    = (const float*)d_in[0];
    const int*   ei   = (const int*)d_in[1];
    const float* W1l  = (const float*)d_in[2];
    const float* b1   = (const float*)d_in[3];
    const float* W1r  = (const float*)d_in[4];
    const float* W2l  = (const float*)d_in[5];
    const float* b2   = (const float*)d_in[6];
    const float* W2r  = (const float*)d_in[7];
    const float* fc1W = (const float*)d_in[8];
    const float* fc1b = (const float*)d_in[9];
    const float* fc2W = (const float*)d_in[10];
    const float* fc2b = (const float*)d_in[11];
    float* out = (float*)d_out;

    const int* src = ei;
    const int* dst = ei + N_EDGES;

    // workspace layout:
    //   h1h (N*64 half, 12.8MB) | h1q (N*64 fp8, 6.4MB) |
    //   stage/csr (NBUCK*CAP uint, 12.8MB) | mean2h (N*64 half, 12.8MB) |
    //   row_start (N) | deg (N) | bcursor (NB) | gsum (64 f32)   (~45MB total)
    __half* h1h    = (__half*)d_ws;
    unsigned char* h1q = (unsigned char*)(h1h + (size_t)N_NODES * 64);
    unsigned int* stage = (unsigned int*)(h1q + (size_t)N_NODES * 64);
    int* csr       = (int*)stage;   // sorted in place by k_bsort
    __half* mean2h = (__half*)(stage + (size_t)NBUCK * CAP);
    int* row_start = (int*)(mean2h + (size_t)N_NODES * 64);
    int* deg       = row_start + N_NODES;
    int* bcursor   = deg + N_NODES;
    float* gsum    = (float*)(bcursor + NBUCK);

    // zero bcursor + gsum (adjacent)
    k_zero<<<1, 256, 0, stream>>>(bcursor, NBUCK + 64);

    k_stage<<<512, 256, 0, stream>>>(src, dst, bcursor, stage);
    k_bsort<<<NBUCK, 512, 0, stream>>>(stage, bcursor, row_start, deg);
    layer1<<<2048, 256, 0, stream>>>(x, row_start, deg, csr, W1l, b1, W1r, h1h, h1q);
    agg2<<<2048, 256, 0, stream>>>(h1q, row_start, deg, csr, mean2h);
    mlp2<<<512, 256, 0, stream>>>(mean2h, h1h, W2l, b2, W2r, gsum);
    head<<<1, 64, 0, stream>>>(gsum, fc1W, fc1b, fc2W, fc2b, out);
}